// Round 1
// baseline (1059.923 us; speedup 1.0000x reference)
//
#include <hip/hip_runtime.h>
#include <hip/hip_bf16.h>
#include <math.h>

// Problem constants
#define BB 32
#define TT 512
#define HH 2048
#define KK 128

// -------------------- Kernel A: logits = hiddens @ W + b --------------------
// grid 256 blocks (64 rows each), 256 threads, micro-tile 4x8 per thread.
__global__ __launch_bounds__(256) void gemm_k(const float* __restrict__ hid,
                                              const float* __restrict__ Wm,
                                              const float* __restrict__ bias,
                                              float* __restrict__ logits,
                                              float* __restrict__ loss_slot) {
    constexpr int HC = 16;
    __shared__ float As[HC][68];   // [h][row], stride 68 keeps 16B alignment + conflict-light
    __shared__ float Bs[HC][132];  // [h][col]
    const int tid = threadIdx.x;
    const int bid = blockIdx.x;
    if (bid == 0 && tid == 0) loss_slot[0] = 0.0f;  // zero loss accumulator
    const int rowBase = bid * 64;
    const int tx = tid & 15, ty = tid >> 4;
    const int ldr = tid >> 2, ldc = tid & 3;   // A staging
    const int wr = tid >> 4, wc = tid & 15;    // B staging

    float acc[4][8];
#pragma unroll
    for (int i = 0; i < 4; i++)
#pragma unroll
        for (int j = 0; j < 8; j++) acc[i][j] = 0.0f;

    for (int h0 = 0; h0 < HH; h0 += HC) {
        float4 av = *(const float4*)(hid + (size_t)(rowBase + ldr) * HH + h0 + ldc * 4);
        float4 bv0 = *(const float4*)(Wm + (size_t)(h0 + wr) * KK + wc * 8);
        float4 bv1 = *(const float4*)(Wm + (size_t)(h0 + wr) * KK + wc * 8 + 4);
        __syncthreads();
        As[ldc * 4 + 0][ldr] = av.x;
        As[ldc * 4 + 1][ldr] = av.y;
        As[ldc * 4 + 2][ldr] = av.z;
        As[ldc * 4 + 3][ldr] = av.w;
        *(float4*)&Bs[wr][wc * 8] = bv0;
        *(float4*)&Bs[wr][wc * 8 + 4] = bv1;
        __syncthreads();
#pragma unroll
        for (int h = 0; h < HC; ++h) {
            float4 a = *(const float4*)&As[h][ty * 4];
            float4 b0 = *(const float4*)&Bs[h][tx * 4];
            float4 b1 = *(const float4*)&Bs[h][tx * 4 + 64];
            float ar[4] = {a.x, a.y, a.z, a.w};
            float br[8] = {b0.x, b0.y, b0.z, b0.w, b1.x, b1.y, b1.z, b1.w};
#pragma unroll
            for (int i = 0; i < 4; i++)
#pragma unroll
                for (int j = 0; j < 8; j++) acc[i][j] = fmaf(ar[i], br[j], acc[i][j]);
        }
    }
    float bb[8];
    {
        float4 b0v = *(const float4*)(bias + tx * 4);
        float4 b1v = *(const float4*)(bias + tx * 4 + 64);
        bb[0] = b0v.x; bb[1] = b0v.y; bb[2] = b0v.z; bb[3] = b0v.w;
        bb[4] = b1v.x; bb[5] = b1v.y; bb[6] = b1v.z; bb[7] = b1v.w;
    }
#pragma unroll
    for (int i = 0; i < 4; i++) {
        int row = rowBase + ty * 4 + i;
        float4 o0 = make_float4(acc[i][0] + bb[0], acc[i][1] + bb[1], acc[i][2] + bb[2], acc[i][3] + bb[3]);
        float4 o1 = make_float4(acc[i][4] + bb[4], acc[i][5] + bb[5], acc[i][6] + bb[6], acc[i][7] + bb[7]);
        *(float4*)(logits + (size_t)row * KK + tx * 4) = o0;
        *(float4*)(logits + (size_t)row * KK + tx * 4 + 64) = o1;
    }
}

// -------------------- Kernel B: sequential scans --------------------
// 64 blocks x 512 threads. Blocks 0..31: forward (logsumexp) scan + gold score
// -> loss atomic. Blocks 32..63: viterbi max-scan -> score history in ws.
struct SMemB {
    float alpha[128];
    float u[128];
    float sc[2][128];
    int mbuf[512];
    float red[8];
    int redi[8];
    float vbuf[128];
};

__global__ __launch_bounds__(512) void scan_k(const float* __restrict__ logits,
                                              const int* __restrict__ mask,
                                              const int* __restrict__ labels,
                                              const float* __restrict__ startT,
                                              const float* __restrict__ endT,
                                              const float* __restrict__ trans,
                                              float* __restrict__ shist,
                                              float* __restrict__ out) {
    __shared__ SMemB sm;
    const int tid = threadIdx.x;
    const int bid = blockIdx.x;
    const float L2E = 1.4426950408889634f;

    if (bid < BB) {
        // ---------- forward (log-partition) ----------
        const int b = bid;
        const int j = tid >> 2, s = tid & 3;
        const float* lrow = logits + (size_t)b * TT * KK;
        // V = exp(trans) slice held in registers: V[k] = e^{trans[s*32+k][j]}
        float V[32];
#pragma unroll
        for (int k = 0; k < 32; k++) V[k] = exp2f(trans[(s * 32 + k) * KK + j] * L2E);
        sm.mbuf[tid] = mask[b * TT + tid];
        if (tid < 128) sm.alpha[tid] = (startT[tid] + lrow[tid]) * L2E;
        __syncthreads();

        double Od = 0.0;  // offset accumulator (thread 0)
        float em_next = lrow[KK + j];
        for (int t = 1; t < TT; ++t) {
            float em = em_next;
            if (t + 1 < TT) em_next = lrow[(size_t)(t + 1) * KK + j];
            int mt = sm.mbuf[t];
            if (mt) {
                float a0 = sm.alpha[0];
                if (tid < 128) sm.u[tid] = exp2f(sm.alpha[tid] - a0);
                if (tid == 0) Od += (double)a0;
                __syncthreads();
                float w = 0.0f;
                const float* ub = &sm.u[s * 32];
#pragma unroll
                for (int k = 0; k < 32; k++) w = fmaf(ub[k], V[k], w);
                w += __shfl_xor(w, 1, 64);
                w += __shfl_xor(w, 2, 64);
                if (s == 0) sm.alpha[j] = log2f(w) + em * L2E;
                __syncthreads();
            }
        }
        if (tid < 128) sm.vbuf[tid] = sm.alpha[tid] + endT[tid] * L2E;

        // gold path score (parallel over t)
        float part = 0.0f;
        int cnt = sm.mbuf[tid];
        if (tid == 0) {
            int l0 = labels[b * TT];
            part = startT[l0] + lrow[l0];
        } else if (sm.mbuf[tid]) {
            int lc = labels[b * TT + tid];
            int lp = labels[b * TT + tid - 1];
            part = trans[lp * KK + lc] + lrow[(size_t)tid * KK + lc];
        }
#pragma unroll
        for (int d = 1; d < 64; d <<= 1) {
            part += __shfl_xor(part, d, 64);
            cnt += __shfl_xor(cnt, d, 64);
        }
        int wid = tid >> 6, lane = tid & 63;
        if (lane == 0) { sm.red[wid] = part; sm.redi[wid] = cnt; }
        __syncthreads();
        if (tid == 0) {
            float score = 0.0f;
            int total = 0;
            for (int i = 0; i < 8; i++) { score += sm.red[i]; total += sm.redi[i]; }
            int last = total - 1;
            score += endT[labels[b * TT + last]];
            float mx = -3.0e38f;
            for (int i = 0; i < 128; i++) mx = fmaxf(mx, sm.vbuf[i]);
            float ssum = 0.0f;
            for (int i = 0; i < 128; i++) ssum += exp2f(sm.vbuf[i] - mx);
            double logZ = (Od + (double)mx + (double)log2f(ssum)) * 0.6931471805599453;
            float llh = score - (float)logZ;
            atomicAdd(out + BB * TT, -llh * (1.0f / 32.0f));
        }
    } else {
        // ---------- viterbi forward (max only; history -> ws) ----------
        const int b = bid - BB;
        const int j = tid >> 2, q = tid & 3;
        const float* lrow = logits + (size_t)b * TT * KK;
        float* hist = shist + (size_t)b * TT * KK;
        float TR[32];
#pragma unroll
        for (int k = 0; k < 32; k++) TR[k] = trans[(q * 32 + k) * KK + j];
        sm.mbuf[tid] = mask[b * TT + tid];
        if (tid < 128) {
            float v = startT[tid] + lrow[tid];
            sm.sc[0][tid] = v;
            hist[tid] = v;
        }
        __syncthreads();
        int cur = 0;
        float em_next = lrow[KK + j];
        for (int t = 1; t < TT; ++t) {
            float em = em_next;
            if (t + 1 < TT) em_next = lrow[(size_t)(t + 1) * KK + j];
            int mt = sm.mbuf[t];
            if (mt) {
                const float* sv = &sm.sc[cur][q * 32];
                float m = -3.0e38f;
#pragma unroll
                for (int k = 0; k < 32; k += 2)
                    m = fmaxf(m, fmaxf(sv[k] + TR[k], sv[k + 1] + TR[k + 1]));
                m = fmaxf(m, __shfl_xor(m, 1, 64));
                m = fmaxf(m, __shfl_xor(m, 2, 64));
                float snew = m + em;
                if (q == 0) {
                    sm.sc[cur ^ 1][j] = snew;
                    hist[(size_t)t * KK + j] = snew;
                }
                cur ^= 1;
            } else {
                if (q == 0) hist[(size_t)t * KK + j] = sm.sc[cur][j];
            }
            __syncthreads();
        }
    }
}

// -------------------- Kernel C: parallel backpointer recompute --------------------
// One block per timestep t (1..511); computes bp[b][t][j] for all b, j.
__global__ __launch_bounds__(256) void bp_k(const float* __restrict__ shist,
                                            const float* __restrict__ trans,
                                            const int* __restrict__ mask,
                                            unsigned char* __restrict__ bp) {
    const int t = blockIdx.x + 1;
    const int tid = threadIdx.x;
    const int j = tid & 127, bg = tid >> 7;
    __shared__ float sc[BB][KK];
    for (int i = tid; i < BB * KK; i += 256) {
        int bb2 = i >> 7;
        sc[bb2][i & 127] = shist[(size_t)bb2 * TT * KK + (size_t)(t - 1) * KK + (i & 127)];
    }
    __syncthreads();
    float m[16];
    int idx[16];
#pragma unroll
    for (int c = 0; c < 16; c++) { m[c] = -3.0e38f; idx[c] = 0; }
#pragma unroll 4
    for (int i = 0; i < 128; ++i) {
        float tr = trans[i * KK + j];
#pragma unroll
        for (int c = 0; c < 16; c++) {
            float cand = sc[bg + 2 * c][i] + tr;
            if (cand > m[c]) { m[c] = cand; idx[c] = i; }  // strict > = first-argmax
        }
    }
#pragma unroll
    for (int c = 0; c < 16; c++) {
        int bb2 = bg + 2 * c;
        int v = idx[c];
        if (mask[bb2 * TT + t] == 0) v = j;
        bp[(size_t)bb2 * TT * KK + (size_t)t * KK + j] = (unsigned char)v;
    }
}

// -------------------- Kernel D: backtrace via 8-wave register relay --------------------
__global__ __launch_bounds__(512) void bt_k(const float* __restrict__ shist,
                                            const float* __restrict__ endT,
                                            const unsigned char* __restrict__ bp,
                                            float* __restrict__ out) {
    const int b = blockIdx.x;
    const int tid = threadIdx.x;
    const int lane = tid & 63, w = tid >> 6;
    __shared__ float cb[128];
    __shared__ int tagbuf[512];
    __shared__ int handoff;
    if (tid < 128) cb[tid] = shist[(size_t)b * TT * KK + (size_t)(TT - 1) * KK + tid] + endT[tid];
    __syncthreads();
    if (tid == 0) {
        float mm = cb[0];
        int bi = 0;
        for (int i = 1; i < 128; i++)
            if (cb[i] > mm) { mm = cb[i]; bi = i; }
        tagbuf[TT - 1] = bi;
        handoff = bi;
    }
    // each wave loads its 64 bp rows: lane holds entries (2*lane, 2*lane+1) as u16
    unsigned int reg[64];
    const unsigned char* bpb = bp + (size_t)b * TT * KK;
#pragma unroll
    for (int r = 0; r < 64; r++) {
        int t_row = w * 64 + 1 + r;
        unsigned int v = 0;
        if (t_row < TT) v = *(const unsigned short*)(bpb + (size_t)t_row * KK + lane * 2);
        reg[r] = v;
    }
    __syncthreads();
    for (int ph = 7; ph >= 0; --ph) {
        if (w == ph) {
            int tag = handoff;
#pragma unroll
            for (int r = 63; r >= 0; --r) {
                int t_row = ph * 64 + 1 + r;
                if (t_row < TT) {
                    unsigned int vv = (unsigned int)__shfl((int)reg[r], tag >> 1, 64);
                    tag = (int)((vv >> ((tag & 1) * 8)) & 0xffu);
                    if (lane == 0) tagbuf[t_row - 1] = tag;
                }
            }
            if (lane == 0) handoff = tag;
        }
        __syncthreads();
    }
    out[b * TT + tid] = (float)tagbuf[tid];
}

// -------------------- launch --------------------
extern "C" void kernel_launch(void* const* d_in, const int* in_sizes, int n_in,
                              void* d_out, int out_size, void* d_ws, size_t ws_size,
                              hipStream_t stream) {
    const float* hid = (const float*)d_in[0];
    const int* mask = (const int*)d_in[1];
    const int* labels = (const int*)d_in[2];
    const float* Wm = (const float*)d_in[3];
    const float* bias = (const float*)d_in[4];
    const float* startT = (const float*)d_in[5];
    const float* endT = (const float*)d_in[6];
    const float* trans = (const float*)d_in[7];
    float* out = (float*)d_out;
    char* ws = (char*)d_ws;

    float* logits = (float*)ws;                              // 8,388,608 B
    float* shist = (float*)(ws + 8388608);                   // 8,388,608 B
    unsigned char* bp = (unsigned char*)(ws + 16777216);     // 2,097,152 B

    gemm_k<<<256, 256, 0, stream>>>(hid, Wm, bias, logits, out + BB * TT);
    scan_k<<<64, 512, 0, stream>>>(logits, mask, labels, startT, endT, trans, shist, out);
    bp_k<<<TT - 1, 256, 0, stream>>>(shist, trans, mask, bp);
    bt_k<<<BB, 512, 0, stream>>>(shist, endT, bp, out);
}

// Round 2
// 708.267 us; speedup vs baseline: 1.4965x; 1.4965x over previous
//
#include <hip/hip_runtime.h>
#include <hip/hip_bf16.h>
#include <math.h>

// Problem constants
#define BB 32
#define TT 512
#define HH 2048
#define KK 128

// -------------------- Kernel A: logits = hiddens @ W + b --------------------
// grid 256 blocks (64 rows each), 256 threads, micro-tile 4x8 per thread.
__global__ __launch_bounds__(256) void gemm_k(const float* __restrict__ hid,
                                              const float* __restrict__ Wm,
                                              const float* __restrict__ bias,
                                              float* __restrict__ logits,
                                              float* __restrict__ loss_slot) {
    constexpr int HC = 16;
    __shared__ float As[HC][68];   // [h][row]
    __shared__ float Bs[HC][132];  // [h][col]
    const int tid = threadIdx.x;
    const int bid = blockIdx.x;
    if (bid == 0 && tid == 0) loss_slot[0] = 0.0f;  // zero loss accumulator
    const int rowBase = bid * 64;
    const int tx = tid & 15, ty = tid >> 4;
    const int ldr = tid >> 2, ldc = tid & 3;   // A staging
    const int wr = tid >> 4, wc = tid & 15;    // B staging

    float acc[4][8];
#pragma unroll
    for (int i = 0; i < 4; i++)
#pragma unroll
        for (int j = 0; j < 8; j++) acc[i][j] = 0.0f;

    for (int h0 = 0; h0 < HH; h0 += HC) {
        float4 av = *(const float4*)(hid + (size_t)(rowBase + ldr) * HH + h0 + ldc * 4);
        float4 bv0 = *(const float4*)(Wm + (size_t)(h0 + wr) * KK + wc * 8);
        float4 bv1 = *(const float4*)(Wm + (size_t)(h0 + wr) * KK + wc * 8 + 4);
        __syncthreads();
        As[ldc * 4 + 0][ldr] = av.x;
        As[ldc * 4 + 1][ldr] = av.y;
        As[ldc * 4 + 2][ldr] = av.z;
        As[ldc * 4 + 3][ldr] = av.w;
        *(float4*)&Bs[wr][wc * 8] = bv0;
        *(float4*)&Bs[wr][wc * 8 + 4] = bv1;
        __syncthreads();
#pragma unroll
        for (int h = 0; h < HC; ++h) {
            float4 a = *(const float4*)&As[h][ty * 4];
            float4 b0 = *(const float4*)&Bs[h][tx * 4];
            float4 b1 = *(const float4*)&Bs[h][tx * 4 + 64];
            float ar[4] = {a.x, a.y, a.z, a.w};
            float br[8] = {b0.x, b0.y, b0.z, b0.w, b1.x, b1.y, b1.z, b1.w};
#pragma unroll
            for (int i = 0; i < 4; i++)
#pragma unroll
                for (int j = 0; j < 8; j++) acc[i][j] = fmaf(ar[i], br[j], acc[i][j]);
        }
    }
    float bb[8];
    {
        float4 b0v = *(const float4*)(bias + tx * 4);
        float4 b1v = *(const float4*)(bias + tx * 4 + 64);
        bb[0] = b0v.x; bb[1] = b0v.y; bb[2] = b0v.z; bb[3] = b0v.w;
        bb[4] = b1v.x; bb[5] = b1v.y; bb[6] = b1v.z; bb[7] = b1v.w;
    }
#pragma unroll
    for (int i = 0; i < 4; i++) {
        int row = rowBase + ty * 4 + i;
        float4 o0 = make_float4(acc[i][0] + bb[0], acc[i][1] + bb[1], acc[i][2] + bb[2], acc[i][3] + bb[3]);
        float4 o1 = make_float4(acc[i][4] + bb[4], acc[i][5] + bb[5], acc[i][6] + bb[6], acc[i][7] + bb[7]);
        *(float4*)(logits + (size_t)row * KK + tx * 4) = o0;
        *(float4*)(logits + (size_t)row * KK + tx * 4 + 64) = o1;
    }
}

// -------------------- Kernel B: sequential scans (restructured) --------------------
// 64 blocks x 256 threads. Blocks 0..31: forward logsumexp scan (log2 domain,
// V=exp2(trans*L2E) in VGPRs). Blocks 32..63: viterbi max scan (trans in VGPRs).
// Thread (jb = tid>>2, s = tid&3) owns columns {2jb, 2jb+1} and k-slice [32s,32s+32).
// LDS vector double-buffered with +4-per-32 padding (slice base stride 36 floats
// -> the 4 uniform b128 addresses per read instr hit 16 distinct banks).
// ONE barrier per step. Offset chain re-derived from u[0] broadcast (no 2nd sync).
struct SMemB {
    float ubuf[2][144];
    int mbuf[512];
    float red[4];
    int redi[4];
    float vbuf[128];
};

__global__ __launch_bounds__(256) void scan_k(const float* __restrict__ logits,
                                              const int* __restrict__ mask,
                                              const int* __restrict__ labels,
                                              const float* __restrict__ startT,
                                              const float* __restrict__ endT,
                                              const float* __restrict__ trans,
                                              float* __restrict__ shist,
                                              float* __restrict__ out) {
    __shared__ SMemB sm;
    const int tid = threadIdx.x;
    const int bid = blockIdx.x;
    const float L2E = 1.4426950408889634f;
    const int s = tid & 3;
    const int jb = tid >> 2;     // 0..63
    const int j0 = jb * 2;
    const int padw = j0 + 4 * (j0 >> 5);  // padded write index for the column pair

    if (bid < BB) {
        // ---------- forward (log-partition), log2 domain ----------
        const int b = bid;
        const float* lrow = logits + (size_t)b * TT * KK;
        float V0[32], V1[32];
#pragma unroll
        for (int k = 0; k < 32; k++) {
            V0[k] = exp2f(trans[(s * 32 + k) * KK + j0] * L2E);
            V1[k] = exp2f(trans[(s * 32 + k) * KK + j0 + 1] * L2E);
        }
        sm.mbuf[tid] = mask[b * TT + tid];
        sm.mbuf[tid + 256] = mask[b * TT + 256 + tid];
        float a0_ = (startT[j0] + lrow[j0]) * L2E;
        float a1_ = (startT[j0 + 1] + lrow[j0 + 1]) * L2E;
        float off = (startT[0] + lrow[0]) * L2E;  // identical on all threads
        if (s == 0) {
            sm.ubuf[0][padw] = exp2f(a0_ - off);
            sm.ubuf[0][padw + 1] = exp2f(a1_ - off);
        }
        __syncthreads();
        int cur = 0;
        float2 em_next = *(const float2*)(lrow + KK + j0);
        for (int t = 1; t < TT; ++t) {
            float2 em = em_next;
            if (t + 1 < TT) em_next = *(const float2*)(lrow + (size_t)(t + 1) * KK + j0);
            if (sm.mbuf[t]) {
                const float* ub = &sm.ubuf[cur][s * 36];
                float u00 = sm.ubuf[cur][0];  // uniform broadcast read
                float uu[32];
#pragma unroll
                for (int c = 0; c < 8; ++c) {
                    float4 v = *(const float4*)(ub + c * 4);
                    uu[c * 4] = v.x; uu[c * 4 + 1] = v.y; uu[c * 4 + 2] = v.z; uu[c * 4 + 3] = v.w;
                }
                float p0e = 0.f, p0o = 0.f, p1e = 0.f, p1o = 0.f;
#pragma unroll
                for (int k = 0; k < 32; k += 2) {
                    p0e = fmaf(uu[k], V0[k], p0e);
                    p1e = fmaf(uu[k], V1[k], p1e);
                    p0o = fmaf(uu[k + 1], V0[k + 1], p0o);
                    p1o = fmaf(uu[k + 1], V1[k + 1], p1o);
                }
                float w0 = p0e + p0o, w1 = p1e + p1o;
                w0 += __shfl_xor(w0, 1, 64);
                w0 += __shfl_xor(w0, 2, 64);
                w1 += __shfl_xor(w1, 1, 64);
                w1 += __shfl_xor(w1, 2, 64);
                a0_ = log2f(w0) + off + em.x * L2E;  // absolute log2-alpha
                a1_ = log2f(w1) + off + em.y * L2E;
                float offn = off + log2f(u00);  // = alpha2_0(t-1), consistent on all threads
                if (s == 0) {
                    sm.ubuf[cur ^ 1][padw] = exp2f(a0_ - offn);
                    sm.ubuf[cur ^ 1][padw + 1] = exp2f(a1_ - offn);
                }
                off = offn;
                cur ^= 1;
                __syncthreads();
            }
        }
        if (s == 0) {
            sm.vbuf[j0] = a0_ + endT[j0] * L2E;
            sm.vbuf[j0 + 1] = a1_ + endT[j0 + 1] * L2E;
        }
        __syncthreads();

        // gold path score (parallel over t, 2 per thread)
        float part = 0.0f;
        int cnt = 0;
        for (int tt = tid; tt < TT; tt += 256) {
            int mv = sm.mbuf[tt];
            cnt += mv;
            if (tt == 0) {
                int l0 = labels[b * TT];
                part += startT[l0] + lrow[l0];
            } else if (mv) {
                int lc = labels[b * TT + tt];
                int lp = labels[b * TT + tt - 1];
                part += trans[lp * KK + lc] + lrow[(size_t)tt * KK + lc];
            }
        }
#pragma unroll
        for (int d = 1; d < 64; d <<= 1) {
            part += __shfl_xor(part, d, 64);
            cnt += __shfl_xor(cnt, d, 64);
        }
        int wid = tid >> 6, lane = tid & 63;
        if (lane == 0) { sm.red[wid] = part; sm.redi[wid] = cnt; }
        __syncthreads();
        if (tid == 0) {
            float score = 0.0f;
            int total = 0;
            for (int i = 0; i < 4; i++) { score += sm.red[i]; total += sm.redi[i]; }
            score += endT[labels[b * TT + total - 1]];
            float mx = -3.0e38f;
            for (int i = 0; i < 128; i++) mx = fmaxf(mx, sm.vbuf[i]);
            float ssum = 0.0f;
            for (int i = 0; i < 128; i++) ssum += exp2f(sm.vbuf[i] - mx);
            float logZ = (mx + log2f(ssum)) * 0.6931471805599453f;
            float llh = score - logZ;
            atomicAdd(out + BB * TT, -llh * (1.0f / 32.0f));
        }
    } else {
        // ---------- viterbi forward (max only; score history -> ws) ----------
        const int b = bid - BB;
        const float* lrow = logits + (size_t)b * TT * KK;
        float* hist = shist + (size_t)b * TT * KK;
        float T0[32], T1[32];
#pragma unroll
        for (int k = 0; k < 32; k++) {
            T0[k] = trans[(s * 32 + k) * KK + j0];
            T1[k] = trans[(s * 32 + k) * KK + j0 + 1];
        }
        sm.mbuf[tid] = mask[b * TT + tid];
        sm.mbuf[tid + 256] = mask[b * TT + 256 + tid];
        float s0_ = startT[j0] + lrow[j0];
        float s1_ = startT[j0 + 1] + lrow[j0 + 1];
        if (s == 0) {
            sm.ubuf[0][padw] = s0_;
            sm.ubuf[0][padw + 1] = s1_;
        } else if (s == 1) {
            *(float2*)(hist + j0) = make_float2(s0_, s1_);
        }
        __syncthreads();
        int cur = 0;
        float2 em_next = *(const float2*)(lrow + KK + j0);
        for (int t = 1; t < TT; ++t) {
            float2 em = em_next;
            if (t + 1 < TT) em_next = *(const float2*)(lrow + (size_t)(t + 1) * KK + j0);
            if (sm.mbuf[t]) {
                const float* ub = &sm.ubuf[cur][s * 36];
                float uu[32];
#pragma unroll
                for (int c = 0; c < 8; ++c) {
                    float4 v = *(const float4*)(ub + c * 4);
                    uu[c * 4] = v.x; uu[c * 4 + 1] = v.y; uu[c * 4 + 2] = v.z; uu[c * 4 + 3] = v.w;
                }
                float m0 = -3.0e38f, m1 = -3.0e38f;
#pragma unroll
                for (int k = 0; k < 32; k += 2) {
                    m0 = fmaxf(m0, fmaxf(uu[k] + T0[k], uu[k + 1] + T0[k + 1]));
                    m1 = fmaxf(m1, fmaxf(uu[k] + T1[k], uu[k + 1] + T1[k + 1]));
                }
                m0 = fmaxf(m0, __shfl_xor(m0, 1, 64));
                m0 = fmaxf(m0, __shfl_xor(m0, 2, 64));
                m1 = fmaxf(m1, __shfl_xor(m1, 1, 64));
                m1 = fmaxf(m1, __shfl_xor(m1, 2, 64));
                s0_ = m0 + em.x;
                s1_ = m1 + em.y;
                if (s == 0) {
                    sm.ubuf[cur ^ 1][padw] = s0_;
                    sm.ubuf[cur ^ 1][padw + 1] = s1_;
                } else if (s == 1) {
                    *(float2*)(hist + (size_t)t * KK + j0) = make_float2(s0_, s1_);
                }
                cur ^= 1;
                __syncthreads();
            } else {
                if (s == 1) *(float2*)(hist + (size_t)t * KK + j0) = make_float2(s0_, s1_);
            }
        }
    }
}

// -------------------- Kernel C: parallel backpointer recompute --------------------
__global__ __launch_bounds__(256) void bp_k(const float* __restrict__ shist,
                                            const float* __restrict__ trans,
                                            const int* __restrict__ mask,
                                            unsigned char* __restrict__ bp) {
    const int t = blockIdx.x + 1;
    const int tid = threadIdx.x;
    const int j = tid & 127, bg = tid >> 7;
    __shared__ float sc[BB][KK];
    for (int i = tid; i < BB * KK; i += 256) {
        int bb2 = i >> 7;
        sc[bb2][i & 127] = shist[(size_t)bb2 * TT * KK + (size_t)(t - 1) * KK + (i & 127)];
    }
    __syncthreads();
    float m[16];
    int idx[16];
#pragma unroll
    for (int c = 0; c < 16; c++) { m[c] = -3.0e38f; idx[c] = 0; }
#pragma unroll 4
    for (int i = 0; i < 128; ++i) {
        float tr = trans[i * KK + j];
#pragma unroll
        for (int c = 0; c < 16; c++) {
            float cand = sc[bg + 2 * c][i] + tr;
            if (cand > m[c]) { m[c] = cand; idx[c] = i; }  // strict > = first-argmax
        }
    }
#pragma unroll
    for (int c = 0; c < 16; c++) {
        int bb2 = bg + 2 * c;
        int v = idx[c];
        if (mask[bb2 * TT + t] == 0) v = j;
        bp[(size_t)bb2 * TT * KK + (size_t)t * KK + j] = (unsigned char)v;
    }
}

// -------------------- Kernel D: backtrace via 8-wave register relay --------------------
__global__ __launch_bounds__(512) void bt_k(const float* __restrict__ shist,
                                            const float* __restrict__ endT,
                                            const unsigned char* __restrict__ bp,
                                            float* __restrict__ out) {
    const int b = blockIdx.x;
    const int tid = threadIdx.x;
    const int lane = tid & 63, w = tid >> 6;
    __shared__ float cb[128];
    __shared__ int tagbuf[512];
    __shared__ int handoff;
    if (tid < 128) cb[tid] = shist[(size_t)b * TT * KK + (size_t)(TT - 1) * KK + tid] + endT[tid];
    __syncthreads();
    if (tid == 0) {
        float mm = cb[0];
        int bi = 0;
        for (int i = 1; i < 128; i++)
            if (cb[i] > mm) { mm = cb[i]; bi = i; }
        tagbuf[TT - 1] = bi;
        handoff = bi;
    }
    unsigned int reg[64];
    const unsigned char* bpb = bp + (size_t)b * TT * KK;
#pragma unroll
    for (int r = 0; r < 64; r++) {
        int t_row = w * 64 + 1 + r;
        unsigned int v = 0;
        if (t_row < TT) v = *(const unsigned short*)(bpb + (size_t)t_row * KK + lane * 2);
        reg[r] = v;
    }
    __syncthreads();
    for (int ph = 7; ph >= 0; --ph) {
        if (w == ph) {
            int tag = handoff;
#pragma unroll
            for (int r = 63; r >= 0; --r) {
                int t_row = ph * 64 + 1 + r;
                if (t_row < TT) {
                    unsigned int vv = (unsigned int)__shfl((int)reg[r], tag >> 1, 64);
                    tag = (int)((vv >> ((tag & 1) * 8)) & 0xffu);
                    if (lane == 0) tagbuf[t_row - 1] = tag;
                }
            }
            if (lane == 0) handoff = tag;
        }
        __syncthreads();
    }
    out[b * TT + tid] = (float)tagbuf[tid];
}

// -------------------- launch --------------------
extern "C" void kernel_launch(void* const* d_in, const int* in_sizes, int n_in,
                              void* d_out, int out_size, void* d_ws, size_t ws_size,
                              hipStream_t stream) {
    const float* hid = (const float*)d_in[0];
    const int* mask = (const int*)d_in[1];
    const int* labels = (const int*)d_in[2];
    const float* Wm = (const float*)d_in[3];
    const float* bias = (const float*)d_in[4];
    const float* startT = (const float*)d_in[5];
    const float* endT = (const float*)d_in[6];
    const float* trans = (const float*)d_in[7];
    float* out = (float*)d_out;
    char* ws = (char*)d_ws;

    float* logits = (float*)ws;                              // 8,388,608 B
    float* shist = (float*)(ws + 8388608);                   // 8,388,608 B
    unsigned char* bp = (unsigned char*)(ws + 16777216);     // 2,097,152 B

    gemm_k<<<256, 256, 0, stream>>>(hid, Wm, bias, logits, out + BB * TT);
    scan_k<<<64, 256, 0, stream>>>(logits, mask, labels, startT, endT, trans, shist, out);
    bp_k<<<TT - 1, 256, 0, stream>>>(shist, trans, mask, bp);
    bt_k<<<BB, 512, 0, stream>>>(shist, endT, bp, out);
}

// Round 3
// 685.762 us; speedup vs baseline: 1.5456x; 1.0328x over previous
//
#include <hip/hip_runtime.h>
#include <hip/hip_bf16.h>
#include <math.h>

// Problem constants
#define BB 32
#define TT 512
#define HH 2048
#define KK 128

// -------------------- Kernel A: logits = hiddens @ W + b --------------------
// 256 blocks x 512 threads. In-block split-K: wave-group g = tid>>7 handles
// h in [g*512, g*512+512). Tile 64 rows x 128 cols, micro-tile 8x8 (LDS bytes
// per FMA = 1.0 -> LDS pipe balanced with FMA pipe). 2 waves/SIMD for latency
// hiding. Deterministic epilogue: acc(g0)+g1, +g2, +g3 via LDS, then +bias.
__global__ __launch_bounds__(512) void gemm_k(const float* __restrict__ hid,
                                              const float* __restrict__ Wm,
                                              const float* __restrict__ bias,
                                              float* __restrict__ logits,
                                              float* __restrict__ loss_slot) {
    __shared__ union {
        struct { float As[4][16][72]; float Bs[4][16][132]; } s;  // 52.2 KB
        float4 red[16][128];                                      // 32 KB
    } sm;
    const int tid = threadIdx.x, bid = blockIdx.x;
    if (bid == 0 && tid == 0) loss_slot[0] = 0.0f;
    const int g = tid >> 7, lt = tid & 127;
    const int rowBase = bid * 64;
    const int rowg = lt >> 4, colg = lt & 15;
    const int arow = lt >> 1, ahq = lt & 1;  // A staging: row, h-half

    float acc[8][8];
#pragma unroll
    for (int i = 0; i < 8; i++)
#pragma unroll
        for (int j = 0; j < 8; j++) acc[i][j] = 0.0f;

    const float* hA = hid + (size_t)(rowBase + arow) * HH + g * 512 + ahq * 8;

    for (int it = 0; it < 32; ++it) {
        const int h0 = g * 512 + it * 16;
        float4 a0 = *(const float4*)(hA + it * 16);
        float4 a1 = *(const float4*)(hA + it * 16 + 4);
        float4 bv[4];
#pragma unroll
        for (int r = 0; r < 4; ++r) {
            int idx = r * 128 + lt;
            bv[r] = *(const float4*)(Wm + (size_t)(h0 + (idx >> 5)) * KK + (idx & 31) * 4);
        }
        __syncthreads();
        const int hb = ahq * 8;
        sm.s.As[g][hb + 0][arow] = a0.x;
        sm.s.As[g][hb + 1][arow] = a0.y;
        sm.s.As[g][hb + 2][arow] = a0.z;
        sm.s.As[g][hb + 3][arow] = a0.w;
        sm.s.As[g][hb + 4][arow] = a1.x;
        sm.s.As[g][hb + 5][arow] = a1.y;
        sm.s.As[g][hb + 6][arow] = a1.z;
        sm.s.As[g][hb + 7][arow] = a1.w;
#pragma unroll
        for (int r = 0; r < 4; ++r) {
            int idx = r * 128 + lt;
            *(float4*)&sm.s.Bs[g][idx >> 5][(idx & 31) * 4] = bv[r];
        }
        __syncthreads();
#pragma unroll
        for (int h = 0; h < 16; ++h) {
            float4 aL = *(const float4*)&sm.s.As[g][h][rowg * 8];
            float4 aH = *(const float4*)&sm.s.As[g][h][rowg * 8 + 4];
            float4 b0 = *(const float4*)&sm.s.Bs[g][h][colg * 4];
            float4 b1 = *(const float4*)&sm.s.Bs[g][h][64 + colg * 4];
            float ar[8] = {aL.x, aL.y, aL.z, aL.w, aH.x, aH.y, aH.z, aH.w};
            float br[8] = {b0.x, b0.y, b0.z, b0.w, b1.x, b1.y, b1.z, b1.w};
#pragma unroll
            for (int i = 0; i < 8; i++)
#pragma unroll
                for (int j = 0; j < 8; j++) acc[i][j] = fmaf(ar[i], br[j], acc[i][j]);
        }
    }
    // Epilogue: deterministic cross-group combine (g0 += g1, then g2, then g3)
    __syncthreads();
    for (int gp = 1; gp <= 3; ++gp) {
        if (g == gp) {
#pragma unroll
            for (int i = 0; i < 8; ++i) {
                sm.red[i * 2][lt] = make_float4(acc[i][0], acc[i][1], acc[i][2], acc[i][3]);
                sm.red[i * 2 + 1][lt] = make_float4(acc[i][4], acc[i][5], acc[i][6], acc[i][7]);
            }
        }
        __syncthreads();
        if (g == 0) {
#pragma unroll
            for (int i = 0; i < 8; ++i) {
                float4 r0 = sm.red[i * 2][lt];
                float4 r1 = sm.red[i * 2 + 1][lt];
                acc[i][0] += r0.x; acc[i][1] += r0.y; acc[i][2] += r0.z; acc[i][3] += r0.w;
                acc[i][4] += r1.x; acc[i][5] += r1.y; acc[i][6] += r1.z; acc[i][7] += r1.w;
            }
        }
        __syncthreads();
    }
    if (g == 0) {
        float4 bb0 = *(const float4*)(bias + colg * 4);
        float4 bb1 = *(const float4*)(bias + 64 + colg * 4);
#pragma unroll
        for (int i = 0; i < 8; ++i) {
            int row = rowBase + rowg * 8 + i;
            *(float4*)(logits + (size_t)row * KK + colg * 4) =
                make_float4(acc[i][0] + bb0.x, acc[i][1] + bb0.y, acc[i][2] + bb0.z, acc[i][3] + bb0.w);
            *(float4*)(logits + (size_t)row * KK + 64 + colg * 4) =
                make_float4(acc[i][4] + bb1.x, acc[i][5] + bb1.y, acc[i][6] + bb1.z, acc[i][7] + bb1.w);
        }
    }
}

// -------------------- Kernel B: sequential scans --------------------
// 64 blocks x 256 threads. Blocks 0..31: forward scan in EXP domain:
//   S_j(t) = [sum_k S_k(t-1) V_kj] * exp2(em_j*L2E) * rcp(S_0(t-1))
// (no transcendental on the critical chain; offset OFF accumulated off-chain).
// Blocks 32..63: viterbi max scan (bitwise-identical values to R2).
// Mask held as an 8xu64 register bitmask (no LDS read / branch stall).
struct SMemB {
    float ubuf[2][144];
    float red[4];
    int redi[4];
    float vbuf[128];
};

__global__ __launch_bounds__(256) void scan_k(const float* __restrict__ logits,
                                              const int* __restrict__ mask,
                                              const int* __restrict__ labels,
                                              const float* __restrict__ startT,
                                              const float* __restrict__ endT,
                                              const float* __restrict__ trans,
                                              float* __restrict__ shist,
                                              float* __restrict__ out) {
    __shared__ SMemB sm;
    const int tid = threadIdx.x;
    const int bid = blockIdx.x;
    const float L2E = 1.4426950408889634f;
    const int s = tid & 3;
    const int jb = tid >> 2;
    const int j0 = jb * 2;
    const int padw = j0 + 4 * (j0 >> 5);
    const int lane = tid & 63;

    if (bid < BB) {
        // ---------- forward (log-partition), exp domain ----------
        const int b = bid;
        const float* lrow = logits + (size_t)b * TT * KK;
        unsigned long long mb[8];
#pragma unroll
        for (int c = 0; c < 8; ++c) mb[c] = __ballot(mask[b * TT + c * 64 + lane]);
        float V0[32], V1[32];
#pragma unroll
        for (int k = 0; k < 32; k++) {
            V0[k] = exp2f(trans[(s * 32 + k) * KK + j0] * L2E);
            V1[k] = exp2f(trans[(s * 32 + k) * KK + j0 + 1] * L2E);
        }
        float a0_ = (startT[j0] + lrow[j0]) * L2E;
        float a1_ = (startT[j0 + 1] + lrow[j0 + 1]) * L2E;
        float OFF = (startT[0] + lrow[0]) * L2E;  // identical on all threads
        float S0_ = exp2f(a0_ - OFF);
        float S1_ = exp2f(a1_ - OFF);
        if (s == 0) {
            sm.ubuf[0][padw] = S0_;
            sm.ubuf[0][padw + 1] = S1_;
        }
        __syncthreads();
        int cur = 0;
        float2 em_next = *(const float2*)(lrow + KK + j0);
        for (int t = 1; t < TT; ++t) {
            float2 em = em_next;
            if (t + 1 < TT) em_next = *(const float2*)(lrow + (size_t)(t + 1) * KK + j0);
            int mt = (int)((mb[t >> 6] >> (t & 63)) & 1ull);
            if (mt) {
                const float* ub = &sm.ubuf[cur][s * 36];
                float u00 = sm.ubuf[cur][0];
                float uu[32];
#pragma unroll
                for (int c = 0; c < 8; ++c) {
                    float4 v = *(const float4*)(ub + c * 4);
                    uu[c * 4] = v.x; uu[c * 4 + 1] = v.y; uu[c * 4 + 2] = v.z; uu[c * 4 + 3] = v.w;
                }
                float r00 = __builtin_amdgcn_rcpf(u00);
                float sc0 = exp2f(em.x * L2E) * r00;
                float sc1 = exp2f(em.y * L2E) * r00;
                OFF += log2f(u00);  // off-chain, uniform across threads
                float p0e = 0.f, p0o = 0.f, p1e = 0.f, p1o = 0.f;
#pragma unroll
                for (int k = 0; k < 32; k += 2) {
                    p0e = fmaf(uu[k], V0[k], p0e);
                    p1e = fmaf(uu[k], V1[k], p1e);
                    p0o = fmaf(uu[k + 1], V0[k + 1], p0o);
                    p1o = fmaf(uu[k + 1], V1[k + 1], p1o);
                }
                float w0 = p0e + p0o, w1 = p1e + p1o;
                w0 += __shfl_xor(w0, 1, 64);
                w0 += __shfl_xor(w0, 2, 64);
                w1 += __shfl_xor(w1, 1, 64);
                w1 += __shfl_xor(w1, 2, 64);
                S0_ = w0 * sc0;
                S1_ = w1 * sc1;
                if (s == 0) {
                    sm.ubuf[cur ^ 1][padw] = S0_;
                    sm.ubuf[cur ^ 1][padw + 1] = S1_;
                }
                cur ^= 1;
            }
            __syncthreads();
        }
        if (s == 0) {
            sm.vbuf[j0] = log2f(S0_) + endT[j0] * L2E;
            sm.vbuf[j0 + 1] = log2f(S1_) + endT[j0 + 1] * L2E;
        }
        __syncthreads();

        // gold path score (parallel over t)
        float part = 0.0f;
        for (int tt = tid; tt < TT; tt += 256) {
            if (tt == 0) {
                int l0 = labels[b * TT];
                part += startT[l0] + lrow[l0];
            } else if (mask[b * TT + tt]) {
                int lc = labels[b * TT + tt];
                int lp = labels[b * TT + tt - 1];
                part += trans[lp * KK + lc] + lrow[(size_t)tt * KK + lc];
            }
        }
#pragma unroll
        for (int d = 1; d < 64; d <<= 1) part += __shfl_xor(part, d, 64);
        int wid = tid >> 6;
        if (lane == 0) sm.red[wid] = part;
        __syncthreads();
        if (tid < 64) {
            float v0 = sm.vbuf[tid], v1 = sm.vbuf[tid + 64];
            float mx = fmaxf(v0, v1);
#pragma unroll
            for (int d = 1; d < 64; d <<= 1) mx = fmaxf(mx, __shfl_xor(mx, d, 64));
            float p = exp2f(v0 - mx) + exp2f(v1 - mx);
#pragma unroll
            for (int d = 1; d < 64; d <<= 1) p += __shfl_xor(p, d, 64);
            if (tid == 0) {
                int total = 0;
#pragma unroll
                for (int c = 0; c < 8; ++c) total += __popcll(mb[c]);
                float score = sm.red[0] + sm.red[1] + sm.red[2] + sm.red[3];
                score += endT[labels[b * TT + total - 1]];
                float logZ = (OFF + mx + log2f(p)) * 0.6931471805599453f;
                float llh = score - logZ;
                atomicAdd(out + BB * TT, -llh * (1.0f / 32.0f));
            }
        }
    } else {
        // ---------- viterbi forward (max only; score history -> ws) ----------
        const int b = bid - BB;
        const float* lrow = logits + (size_t)b * TT * KK;
        float* hist = shist + (size_t)b * TT * KK;
        unsigned long long mb[8];
#pragma unroll
        for (int c = 0; c < 8; ++c) mb[c] = __ballot(mask[b * TT + c * 64 + lane]);
        float T0[32], T1[32];
#pragma unroll
        for (int k = 0; k < 32; k++) {
            T0[k] = trans[(s * 32 + k) * KK + j0];
            T1[k] = trans[(s * 32 + k) * KK + j0 + 1];
        }
        float s0_ = startT[j0] + lrow[j0];
        float s1_ = startT[j0 + 1] + lrow[j0 + 1];
        if (s == 0) {
            sm.ubuf[0][padw] = s0_;
            sm.ubuf[0][padw + 1] = s1_;
        } else if (s == 1) {
            *(float2*)(hist + j0) = make_float2(s0_, s1_);
        }
        __syncthreads();
        int cur = 0;
        float2 em_next = *(const float2*)(lrow + KK + j0);
        for (int t = 1; t < TT; ++t) {
            float2 em = em_next;
            if (t + 1 < TT) em_next = *(const float2*)(lrow + (size_t)(t + 1) * KK + j0);
            int mt = (int)((mb[t >> 6] >> (t & 63)) & 1ull);
            if (mt) {
                const float* ub = &sm.ubuf[cur][s * 36];
                float uu[32];
#pragma unroll
                for (int c = 0; c < 8; ++c) {
                    float4 v = *(const float4*)(ub + c * 4);
                    uu[c * 4] = v.x; uu[c * 4 + 1] = v.y; uu[c * 4 + 2] = v.z; uu[c * 4 + 3] = v.w;
                }
                float m0 = -3.0e38f, m1 = -3.0e38f;
#pragma unroll
                for (int k = 0; k < 32; k += 2) {
                    m0 = fmaxf(m0, fmaxf(uu[k] + T0[k], uu[k + 1] + T0[k + 1]));
                    m1 = fmaxf(m1, fmaxf(uu[k] + T1[k], uu[k + 1] + T1[k + 1]));
                }
                m0 = fmaxf(m0, __shfl_xor(m0, 1, 64));
                m0 = fmaxf(m0, __shfl_xor(m0, 2, 64));
                m1 = fmaxf(m1, __shfl_xor(m1, 1, 64));
                m1 = fmaxf(m1, __shfl_xor(m1, 2, 64));
                s0_ = m0 + em.x;
                s1_ = m1 + em.y;
                if (s == 0) {
                    sm.ubuf[cur ^ 1][padw] = s0_;
                    sm.ubuf[cur ^ 1][padw + 1] = s1_;
                } else if (s == 1) {
                    *(float2*)(hist + (size_t)t * KK + j0) = make_float2(s0_, s1_);
                }
                cur ^= 1;
            } else {
                if (s == 1) *(float2*)(hist + (size_t)t * KK + j0) = make_float2(s0_, s1_);
            }
            __syncthreads();
        }
    }
}

// -------------------- Kernel C: parallel backpointer recompute --------------------
__global__ __launch_bounds__(256) void bp_k(const float* __restrict__ shist,
                                            const float* __restrict__ trans,
                                            const int* __restrict__ mask,
                                            unsigned char* __restrict__ bp) {
    const int t = blockIdx.x + 1;
    const int tid = threadIdx.x;
    const int j = tid & 127, bg = tid >> 7;
    __shared__ float sc[BB][KK];
#pragma unroll
    for (int r = 0; r < 4; ++r) {
        int f = tid + r * 256;
        int bb2 = f >> 5, c4 = (f & 31) * 4;
        *(float4*)&sc[bb2][c4] = *(const float4*)&shist[(size_t)bb2 * TT * KK + (size_t)(t - 1) * KK + c4];
    }
    __syncthreads();
    float m[16];
    int idx[16];
#pragma unroll
    for (int c = 0; c < 16; c++) { m[c] = -3.0e38f; idx[c] = 0; }
    for (int i4 = 0; i4 < 32; ++i4) {
        const int ib = i4 * 4;
        float tr0 = trans[(ib + 0) * KK + j];
        float tr1 = trans[(ib + 1) * KK + j];
        float tr2 = trans[(ib + 2) * KK + j];
        float tr3 = trans[(ib + 3) * KK + j];
#pragma unroll
        for (int c = 0; c < 16; c++) {
            float4 s4 = *(const float4*)&sc[bg + 2 * c][ib];
            float c0 = s4.x + tr0, c1 = s4.y + tr1, c2 = s4.z + tr2, c3 = s4.w + tr3;
            if (c0 > m[c]) { m[c] = c0; idx[c] = ib; }
            if (c1 > m[c]) { m[c] = c1; idx[c] = ib + 1; }
            if (c2 > m[c]) { m[c] = c2; idx[c] = ib + 2; }
            if (c3 > m[c]) { m[c] = c3; idx[c] = ib + 3; }
        }
    }
#pragma unroll
    for (int c = 0; c < 16; c++) {
        int bb2 = bg + 2 * c;
        int v = idx[c];
        if (mask[bb2 * TT + t] == 0) v = j;
        bp[(size_t)bb2 * TT * KK + (size_t)t * KK + j] = (unsigned char)v;
    }
}

// -------------------- Kernel D: backtrace via 8-wave register relay --------------------
__global__ __launch_bounds__(512) void bt_k(const float* __restrict__ shist,
                                            const float* __restrict__ endT,
                                            const unsigned char* __restrict__ bp,
                                            float* __restrict__ out) {
    const int b = blockIdx.x;
    const int tid = threadIdx.x;
    const int lane = tid & 63, w = tid >> 6;
    __shared__ float cb[128];
    __shared__ int tagbuf[512];
    __shared__ int handoff;
    if (tid < 128) cb[tid] = shist[(size_t)b * TT * KK + (size_t)(TT - 1) * KK + tid] + endT[tid];
    __syncthreads();
    if (tid == 0) {
        float mm = cb[0];
        int bi = 0;
        for (int i = 1; i < 128; i++)
            if (cb[i] > mm) { mm = cb[i]; bi = i; }
        tagbuf[TT - 1] = bi;
        handoff = bi;
    }
    unsigned int reg[64];
    const unsigned char* bpb = bp + (size_t)b * TT * KK;
#pragma unroll
    for (int r = 0; r < 64; r++) {
        int t_row = w * 64 + 1 + r;
        unsigned int v = 0;
        if (t_row < TT) v = *(const unsigned short*)(bpb + (size_t)t_row * KK + lane * 2);
        reg[r] = v;
    }
    __syncthreads();
    for (int ph = 7; ph >= 0; --ph) {
        if (w == ph) {
            int tag = handoff;
#pragma unroll
            for (int r = 63; r >= 0; --r) {
                int t_row = ph * 64 + 1 + r;
                if (t_row < TT) {
                    unsigned int vv = (unsigned int)__shfl((int)reg[r], tag >> 1, 64);
                    tag = (int)((vv >> ((tag & 1) * 8)) & 0xffu);
                    if (lane == 0) tagbuf[t_row - 1] = tag;
                }
            }
            if (lane == 0) handoff = tag;
        }
        __syncthreads();
    }
    out[b * TT + tid] = (float)tagbuf[tid];
}

// -------------------- launch --------------------
extern "C" void kernel_launch(void* const* d_in, const int* in_sizes, int n_in,
                              void* d_out, int out_size, void* d_ws, size_t ws_size,
                              hipStream_t stream) {
    const float* hid = (const float*)d_in[0];
    const int* mask = (const int*)d_in[1];
    const int* labels = (const int*)d_in[2];
    const float* Wm = (const float*)d_in[3];
    const float* bias = (const float*)d_in[4];
    const float* startT = (const float*)d_in[5];
    const float* endT = (const float*)d_in[6];
    const float* trans = (const float*)d_in[7];
    float* out = (float*)d_out;
    char* ws = (char*)d_ws;

    float* logits = (float*)ws;                              // 8,388,608 B
    float* shist = (float*)(ws + 8388608);                   // 8,388,608 B
    unsigned char* bp = (unsigned char*)(ws + 16777216);     // 2,097,152 B

    gemm_k<<<256, 512, 0, stream>>>(hid, Wm, bias, logits, out + BB * TT);
    scan_k<<<64, 256, 0, stream>>>(logits, mask, labels, startT, endT, trans, shist, out);
    bp_k<<<TT - 1, 256, 0, stream>>>(shist, trans, mask, bp);
    bt_k<<<BB, 512, 0, stream>>>(shist, endT, bp, out);
}

// Round 4
// 665.394 us; speedup vs baseline: 1.5929x; 1.0306x over previous
//
#include <hip/hip_runtime.h>
#include <hip/hip_bf16.h>
#include <math.h>

// Problem constants
#define BB 32
#define TT 512
#define HH 2048
#define KK 128

// -------------------- Kernel A: logits = hiddens @ W + b --------------------
// 256 blocks x 512 threads, in-block split-K (4 wave-groups x K=512).
// Software-pipelined: global loads for it+1 issue before compute(it), giving
// ~4000 cyc of compute to cover HBM latency (was ~0 -> ~900 cyc stall/it).
__global__ __launch_bounds__(512) void gemm_k(const float* __restrict__ hid,
                                              const float* __restrict__ Wm,
                                              const float* __restrict__ bias,
                                              float* __restrict__ logits,
                                              float* __restrict__ loss_slot) {
    __shared__ union {
        struct { float As[4][16][72]; float Bs[4][16][132]; } s;  // 52.2 KB
        float4 red[16][128];                                      // 32 KB
    } sm;
    const int tid = threadIdx.x, bid = blockIdx.x;
    if (bid == 0 && tid == 0) loss_slot[0] = 0.0f;
    const int g = tid >> 7, lt = tid & 127;
    const int rowBase = bid * 64;
    const int rowg = lt >> 4, colg = lt & 15;
    const int arow = lt >> 1, ahq = lt & 1;  // A staging: row, h-half

    float acc[8][8];
#pragma unroll
    for (int i = 0; i < 8; i++)
#pragma unroll
        for (int j = 0; j < 8; j++) acc[i][j] = 0.0f;

    const float* hA = hid + (size_t)(rowBase + arow) * HH + g * 512 + ahq * 8;

    float4 a0, a1, bv[4];
    // preload it=0
    {
        const int h0 = g * 512;
        a0 = *(const float4*)(hA);
        a1 = *(const float4*)(hA + 4);
#pragma unroll
        for (int r = 0; r < 4; ++r) {
            int idx = r * 128 + lt;
            bv[r] = *(const float4*)(Wm + (size_t)(h0 + (idx >> 5)) * KK + (idx & 31) * 4);
        }
    }

    for (int it = 0; it < 32; ++it) {
        __syncthreads();
        const int hb = ahq * 8;
        sm.s.As[g][hb + 0][arow] = a0.x;
        sm.s.As[g][hb + 1][arow] = a0.y;
        sm.s.As[g][hb + 2][arow] = a0.z;
        sm.s.As[g][hb + 3][arow] = a0.w;
        sm.s.As[g][hb + 4][arow] = a1.x;
        sm.s.As[g][hb + 5][arow] = a1.y;
        sm.s.As[g][hb + 6][arow] = a1.z;
        sm.s.As[g][hb + 7][arow] = a1.w;
#pragma unroll
        for (int r = 0; r < 4; ++r) {
            int idx = r * 128 + lt;
            *(float4*)&sm.s.Bs[g][idx >> 5][(idx & 31) * 4] = bv[r];
        }
        __syncthreads();
        // prefetch it+1 (lands during compute below)
        if (it + 1 < 32) {
            const int h0 = g * 512 + (it + 1) * 16;
            a0 = *(const float4*)(hA + (it + 1) * 16);
            a1 = *(const float4*)(hA + (it + 1) * 16 + 4);
#pragma unroll
            for (int r = 0; r < 4; ++r) {
                int idx = r * 128 + lt;
                bv[r] = *(const float4*)(Wm + (size_t)(h0 + (idx >> 5)) * KK + (idx & 31) * 4);
            }
        }
#pragma unroll
        for (int h = 0; h < 16; ++h) {
            float4 aL = *(const float4*)&sm.s.As[g][h][rowg * 8];
            float4 aH = *(const float4*)&sm.s.As[g][h][rowg * 8 + 4];
            float4 b0 = *(const float4*)&sm.s.Bs[g][h][colg * 4];
            float4 b1 = *(const float4*)&sm.s.Bs[g][h][64 + colg * 4];
            float ar[8] = {aL.x, aL.y, aL.z, aL.w, aH.x, aH.y, aH.z, aH.w};
            float br[8] = {b0.x, b0.y, b0.z, b0.w, b1.x, b1.y, b1.z, b1.w};
#pragma unroll
            for (int i = 0; i < 8; i++)
#pragma unroll
                for (int j = 0; j < 8; j++) acc[i][j] = fmaf(ar[i], br[j], acc[i][j]);
        }
    }
    // Epilogue: deterministic cross-group combine (g0 += g1, then g2, then g3)
    __syncthreads();
    for (int gp = 1; gp <= 3; ++gp) {
        if (g == gp) {
#pragma unroll
            for (int i = 0; i < 8; ++i) {
                sm.red[i * 2][lt] = make_float4(acc[i][0], acc[i][1], acc[i][2], acc[i][3]);
                sm.red[i * 2 + 1][lt] = make_float4(acc[i][4], acc[i][5], acc[i][6], acc[i][7]);
            }
        }
        __syncthreads();
        if (g == 0) {
#pragma unroll
            for (int i = 0; i < 8; ++i) {
                float4 r0 = sm.red[i * 2][lt];
                float4 r1 = sm.red[i * 2 + 1][lt];
                acc[i][0] += r0.x; acc[i][1] += r0.y; acc[i][2] += r0.z; acc[i][3] += r0.w;
                acc[i][4] += r1.x; acc[i][5] += r1.y; acc[i][6] += r1.z; acc[i][7] += r1.w;
            }
        }
        __syncthreads();
    }
    if (g == 0) {
        float4 bb0 = *(const float4*)(bias + colg * 4);
        float4 bb1 = *(const float4*)(bias + 64 + colg * 4);
#pragma unroll
        for (int i = 0; i < 8; ++i) {
            int row = rowBase + rowg * 8 + i;
            *(float4*)(logits + (size_t)row * KK + colg * 4) =
                make_float4(acc[i][0] + bb0.x, acc[i][1] + bb0.y, acc[i][2] + bb0.z, acc[i][3] + bb0.w);
            *(float4*)(logits + (size_t)row * KK + 64 + colg * 4) =
                make_float4(acc[i][4] + bb1.x, acc[i][5] + bb1.y, acc[i][6] + bb1.z, acc[i][7] + bb1.w);
        }
    }
}

// -------------------- Kernel B: sequential scans --------------------
// 64 blocks x 256 threads. Blocks 0..31: forward scan in EXP domain.
// Blocks 32..63: viterbi max scan. Emissions prefetched 4 steps deep in a
// statically-shifted register ring (removes per-step vmcnt stall on the
// serial chain); forward's exp2 scale computed one step ahead.
struct SMemB {
    float ubuf[2][144];
    float red[4];
    float vbuf[128];
};

__global__ __launch_bounds__(256) void scan_k(const float* __restrict__ logits,
                                              const int* __restrict__ mask,
                                              const int* __restrict__ labels,
                                              const float* __restrict__ startT,
                                              const float* __restrict__ endT,
                                              const float* __restrict__ trans,
                                              float* __restrict__ shist,
                                              float* __restrict__ out) {
    __shared__ SMemB sm;
    const int tid = threadIdx.x;
    const int bid = blockIdx.x;
    const float L2E = 1.4426950408889634f;
    const int s = tid & 3;
    const int jb = tid >> 2;
    const int j0 = jb * 2;
    const int padw = j0 + 4 * (j0 >> 5);
    const int lane = tid & 63;

    if (bid < BB) {
        // ---------- forward (log-partition), exp domain ----------
        const int b = bid;
        const float* lrow = logits + (size_t)b * TT * KK;
        unsigned long long mb[8];
#pragma unroll
        for (int c = 0; c < 8; ++c) mb[c] = __ballot(mask[b * TT + c * 64 + lane]);
        float V0[32], V1[32];
#pragma unroll
        for (int k = 0; k < 32; k++) {
            V0[k] = exp2f(trans[(s * 32 + k) * KK + j0] * L2E);
            V1[k] = exp2f(trans[(s * 32 + k) * KK + j0 + 1] * L2E);
        }
        float a0_ = (startT[j0] + lrow[j0]) * L2E;
        float a1_ = (startT[j0 + 1] + lrow[j0 + 1]) * L2E;
        float OFF = (startT[0] + lrow[0]) * L2E;  // identical on all threads
        float S0_ = exp2f(a0_ - OFF);
        float S1_ = exp2f(a1_ - OFF);
        if (s == 0) {
            sm.ubuf[0][padw] = S0_;
            sm.ubuf[0][padw + 1] = S1_;
        }
        // 4-deep emission prefetch ring
        float2 emq[4];
#pragma unroll
        for (int d = 0; d < 4; ++d) emq[d] = *(const float2*)(lrow + (size_t)(1 + d) * KK + j0);
        float2 scc = make_float2(exp2f(emq[0].x * L2E), exp2f(emq[0].y * L2E));  // scale for t=1
        __syncthreads();
        int cur = 0;
        for (int t = 1; t < TT; ++t) {
            float2 sc = scc;
            // shift ring; prefetch t+4; compute next step's scale from emq[0] (loaded 3 steps ago)
            emq[0] = emq[1]; emq[1] = emq[2]; emq[2] = emq[3];
            if (t + 4 < TT) emq[3] = *(const float2*)(lrow + (size_t)(t + 4) * KK + j0);
            scc = make_float2(exp2f(emq[0].x * L2E), exp2f(emq[0].y * L2E));
            int mt = (int)((mb[t >> 6] >> (t & 63)) & 1ull);
            if (mt) {
                const float* ub = &sm.ubuf[cur][s * 36];
                float u00 = sm.ubuf[cur][0];
                float uu[32];
#pragma unroll
                for (int c = 0; c < 8; ++c) {
                    float4 v = *(const float4*)(ub + c * 4);
                    uu[c * 4] = v.x; uu[c * 4 + 1] = v.y; uu[c * 4 + 2] = v.z; uu[c * 4 + 3] = v.w;
                }
                float r00 = __builtin_amdgcn_rcpf(u00);
                OFF += log2f(u00);  // off-chain, uniform across threads
                float p0[4] = {0.f, 0.f, 0.f, 0.f}, p1[4] = {0.f, 0.f, 0.f, 0.f};
#pragma unroll
                for (int k = 0; k < 32; k += 4) {
#pragma unroll
                    for (int q = 0; q < 4; ++q) {
                        p0[q] = fmaf(uu[k + q], V0[k + q], p0[q]);
                        p1[q] = fmaf(uu[k + q], V1[k + q], p1[q]);
                    }
                }
                float w0 = (p0[0] + p0[1]) + (p0[2] + p0[3]);
                float w1 = (p1[0] + p1[1]) + (p1[2] + p1[3]);
                w0 += __shfl_xor(w0, 1, 64);
                w0 += __shfl_xor(w0, 2, 64);
                w1 += __shfl_xor(w1, 1, 64);
                w1 += __shfl_xor(w1, 2, 64);
                S0_ = w0 * (sc.x * r00);
                S1_ = w1 * (sc.y * r00);
                if (s == 0) {
                    sm.ubuf[cur ^ 1][padw] = S0_;
                    sm.ubuf[cur ^ 1][padw + 1] = S1_;
                }
                cur ^= 1;
            }
            __syncthreads();
        }
        if (s == 0) {
            sm.vbuf[j0] = log2f(S0_) + endT[j0] * L2E;
            sm.vbuf[j0 + 1] = log2f(S1_) + endT[j0 + 1] * L2E;
        }
        __syncthreads();

        // gold path score (parallel over t)
        float part = 0.0f;
        for (int tt = tid; tt < TT; tt += 256) {
            if (tt == 0) {
                int l0 = labels[b * TT];
                part += startT[l0] + lrow[l0];
            } else if (mask[b * TT + tt]) {
                int lc = labels[b * TT + tt];
                int lp = labels[b * TT + tt - 1];
                part += trans[lp * KK + lc] + lrow[(size_t)tt * KK + lc];
            }
        }
#pragma unroll
        for (int d = 1; d < 64; d <<= 1) part += __shfl_xor(part, d, 64);
        int wid = tid >> 6;
        if (lane == 0) sm.red[wid] = part;
        __syncthreads();
        if (tid < 64) {
            float v0 = sm.vbuf[tid], v1 = sm.vbuf[tid + 64];
            float mx = fmaxf(v0, v1);
#pragma unroll
            for (int d = 1; d < 64; d <<= 1) mx = fmaxf(mx, __shfl_xor(mx, d, 64));
            float p = exp2f(v0 - mx) + exp2f(v1 - mx);
#pragma unroll
            for (int d = 1; d < 64; d <<= 1) p += __shfl_xor(p, d, 64);
            if (tid == 0) {
                int total = 0;
#pragma unroll
                for (int c = 0; c < 8; ++c) total += __popcll(mb[c]);
                float score = sm.red[0] + sm.red[1] + sm.red[2] + sm.red[3];
                score += endT[labels[b * TT + total - 1]];
                float logZ = (OFF + mx + log2f(p)) * 0.6931471805599453f;
                float llh = score - logZ;
                atomicAdd(out + BB * TT, -llh * (1.0f / 32.0f));
            }
        }
    } else {
        // ---------- viterbi forward (max only; score history -> ws) ----------
        const int b = bid - BB;
        const float* lrow = logits + (size_t)b * TT * KK;
        float* hist = shist + (size_t)b * TT * KK;
        unsigned long long mb[8];
#pragma unroll
        for (int c = 0; c < 8; ++c) mb[c] = __ballot(mask[b * TT + c * 64 + lane]);
        float T0[32], T1[32];
#pragma unroll
        for (int k = 0; k < 32; k++) {
            T0[k] = trans[(s * 32 + k) * KK + j0];
            T1[k] = trans[(s * 32 + k) * KK + j0 + 1];
        }
        float s0_ = startT[j0] + lrow[j0];
        float s1_ = startT[j0 + 1] + lrow[j0 + 1];
        if (s == 0) {
            sm.ubuf[0][padw] = s0_;
            sm.ubuf[0][padw + 1] = s1_;
        } else if (s == 1) {
            *(float2*)(hist + j0) = make_float2(s0_, s1_);
        }
        float2 emq[4];
#pragma unroll
        for (int d = 0; d < 4; ++d) emq[d] = *(const float2*)(lrow + (size_t)(1 + d) * KK + j0);
        __syncthreads();
        int cur = 0;
        for (int t = 1; t < TT; ++t) {
            float2 em = emq[0];
            emq[0] = emq[1]; emq[1] = emq[2]; emq[2] = emq[3];
            if (t + 4 < TT) emq[3] = *(const float2*)(lrow + (size_t)(t + 4) * KK + j0);
            int mt = (int)((mb[t >> 6] >> (t & 63)) & 1ull);
            if (mt) {
                const float* ub = &sm.ubuf[cur][s * 36];
                float uu[32];
#pragma unroll
                for (int c = 0; c < 8; ++c) {
                    float4 v = *(const float4*)(ub + c * 4);
                    uu[c * 4] = v.x; uu[c * 4 + 1] = v.y; uu[c * 4 + 2] = v.z; uu[c * 4 + 3] = v.w;
                }
                float m0a = -3.0e38f, m0b = -3.0e38f, m1a = -3.0e38f, m1b = -3.0e38f;
#pragma unroll
                for (int k = 0; k < 32; k += 4) {
                    m0a = fmaxf(m0a, fmaxf(uu[k] + T0[k], uu[k + 1] + T0[k + 1]));
                    m0b = fmaxf(m0b, fmaxf(uu[k + 2] + T0[k + 2], uu[k + 3] + T0[k + 3]));
                    m1a = fmaxf(m1a, fmaxf(uu[k] + T1[k], uu[k + 1] + T1[k + 1]));
                    m1b = fmaxf(m1b, fmaxf(uu[k + 2] + T1[k + 2], uu[k + 3] + T1[k + 3]));
                }
                float m0 = fmaxf(m0a, m0b), m1 = fmaxf(m1a, m1b);
                m0 = fmaxf(m0, __shfl_xor(m0, 1, 64));
                m0 = fmaxf(m0, __shfl_xor(m0, 2, 64));
                m1 = fmaxf(m1, __shfl_xor(m1, 1, 64));
                m1 = fmaxf(m1, __shfl_xor(m1, 2, 64));
                s0_ = m0 + em.x;
                s1_ = m1 + em.y;
                if (s == 0) {
                    sm.ubuf[cur ^ 1][padw] = s0_;
                    sm.ubuf[cur ^ 1][padw + 1] = s1_;
                } else if (s == 1) {
                    *(float2*)(hist + (size_t)t * KK + j0) = make_float2(s0_, s1_);
                }
                cur ^= 1;
            } else {
                if (s == 1) *(float2*)(hist + (size_t)t * KK + j0) = make_float2(s0_, s1_);
            }
            __syncthreads();
        }
    }
}

// -------------------- Kernel C: parallel backpointer recompute --------------------
__global__ __launch_bounds__(256) void bp_k(const float* __restrict__ shist,
                                            const float* __restrict__ trans,
                                            const int* __restrict__ mask,
                                            unsigned char* __restrict__ bp) {
    const int t = blockIdx.x + 1;
    const int tid = threadIdx.x;
    const int j = tid & 127, bg = tid >> 7;
    __shared__ float sc[BB][KK];
#pragma unroll
    for (int r = 0; r < 4; ++r) {
        int f = tid + r * 256;
        int bb2 = f >> 5, c4 = (f & 31) * 4;
        *(float4*)&sc[bb2][c4] = *(const float4*)&shist[(size_t)bb2 * TT * KK + (size_t)(t - 1) * KK + c4];
    }
    __syncthreads();
    float m[16];
    int idx[16];
#pragma unroll
    for (int c = 0; c < 16; c++) { m[c] = -3.0e38f; idx[c] = 0; }
    for (int i4 = 0; i4 < 32; ++i4) {
        const int ib = i4 * 4;
        float tr0 = trans[(ib + 0) * KK + j];
        float tr1 = trans[(ib + 1) * KK + j];
        float tr2 = trans[(ib + 2) * KK + j];
        float tr3 = trans[(ib + 3) * KK + j];
#pragma unroll
        for (int c = 0; c < 16; c++) {
            float4 s4 = *(const float4*)&sc[bg + 2 * c][ib];
            float c0 = s4.x + tr0, c1 = s4.y + tr1, c2 = s4.z + tr2, c3 = s4.w + tr3;
            if (c0 > m[c]) { m[c] = c0; idx[c] = ib; }
            if (c1 > m[c]) { m[c] = c1; idx[c] = ib + 1; }
            if (c2 > m[c]) { m[c] = c2; idx[c] = ib + 2; }
            if (c3 > m[c]) { m[c] = c3; idx[c] = ib + 3; }
        }
    }
#pragma unroll
    for (int c = 0; c < 16; c++) {
        int bb2 = bg + 2 * c;
        int v = idx[c];
        if (mask[bb2 * TT + t] == 0) v = j;
        bp[(size_t)bb2 * TT * KK + (size_t)t * KK + j] = (unsigned char)v;
    }
}

// -------------------- Kernel D: backtrace via 8-wave register relay --------------------
__global__ __launch_bounds__(512) void bt_k(const float* __restrict__ shist,
                                            const float* __restrict__ endT,
                                            const unsigned char* __restrict__ bp,
                                            float* __restrict__ out) {
    const int b = blockIdx.x;
    const int tid = threadIdx.x;
    const int lane = tid & 63, w = tid >> 6;
    __shared__ float cb[128];
    __shared__ int tagbuf[512];
    __shared__ int handoff;
    if (tid < 128) cb[tid] = shist[(size_t)b * TT * KK + (size_t)(TT - 1) * KK + tid] + endT[tid];
    __syncthreads();
    if (tid == 0) {
        float mm = cb[0];
        int bi = 0;
        for (int i = 1; i < 128; i++)
            if (cb[i] > mm) { mm = cb[i]; bi = i; }
        tagbuf[TT - 1] = bi;
        handoff = bi;
    }
    unsigned int reg[64];
    const unsigned char* bpb = bp + (size_t)b * TT * KK;
#pragma unroll
    for (int r = 0; r < 64; r++) {
        int t_row = w * 64 + 1 + r;
        unsigned int v = 0;
        if (t_row < TT) v = *(const unsigned short*)(bpb + (size_t)t_row * KK + lane * 2);
        reg[r] = v;
    }
    __syncthreads();
    for (int ph = 7; ph >= 0; --ph) {
        if (w == ph) {
            int tag = handoff;
#pragma unroll
            for (int r = 63; r >= 0; --r) {
                int t_row = ph * 64 + 1 + r;
                if (t_row < TT) {
                    unsigned int vv = (unsigned int)__shfl((int)reg[r], tag >> 1, 64);
                    tag = (int)((vv >> ((tag & 1) * 8)) & 0xffu);
                    if (lane == 0) tagbuf[t_row - 1] = tag;
                }
            }
            if (lane == 0) handoff = tag;
        }
        __syncthreads();
    }
    out[b * TT + tid] = (float)tagbuf[tid];
}

// -------------------- launch --------------------
extern "C" void kernel_launch(void* const* d_in, const int* in_sizes, int n_in,
                              void* d_out, int out_size, void* d_ws, size_t ws_size,
                              hipStream_t stream) {
    const float* hid = (const float*)d_in[0];
    const int* mask = (const int*)d_in[1];
    const int* labels = (const int*)d_in[2];
    const float* Wm = (const float*)d_in[3];
    const float* bias = (const float*)d_in[4];
    const float* startT = (const float*)d_in[5];
    const float* endT = (const float*)d_in[6];
    const float* trans = (const float*)d_in[7];
    float* out = (float*)d_out;
    char* ws = (char*)d_ws;

    float* logits = (float*)ws;                              // 8,388,608 B
    float* shist = (float*)(ws + 8388608);                   // 8,388,608 B
    unsigned char* bp = (unsigned char*)(ws + 16777216);     // 2,097,152 B

    gemm_k<<<256, 512, 0, stream>>>(hid, Wm, bias, logits, out + BB * TT);
    scan_k<<<64, 256, 0, stream>>>(logits, mask, labels, startT, endT, trans, shist, out);
    bp_k<<<TT - 1, 256, 0, stream>>>(shist, trans, mask, bp);
    bt_k<<<BB, 512, 0, stream>>>(shist, endT, bp, out);
}

// Round 5
// 657.208 us; speedup vs baseline: 1.6128x; 1.0125x over previous
//
#include <hip/hip_runtime.h>
#include <hip/hip_bf16.h>
#include <math.h>

// Problem constants
#define BB 32
#define TT 512
#define HH 2048
#define KK 128
#define CH 8   // scan chunk size (steps per emission-staging chunk)

// -------------------- Kernel A: logits = hiddens @ W + b --------------------
// 256 blocks x 512 threads, in-block split-K (4 wave-groups x K=512).
__global__ __launch_bounds__(512) void gemm_k(const float* __restrict__ hid,
                                              const float* __restrict__ Wm,
                                              const float* __restrict__ bias,
                                              float* __restrict__ logits,
                                              float* __restrict__ loss_slot) {
    __shared__ union {
        struct { float As[4][16][72]; float Bs[4][16][132]; } s;  // 52.2 KB
        float4 red[16][128];                                      // 32 KB
    } sm;
    const int tid = threadIdx.x, bid = blockIdx.x;
    if (bid == 0 && tid == 0) loss_slot[0] = 0.0f;
    const int g = tid >> 7, lt = tid & 127;
    const int rowBase = bid * 64;
    const int rowg = lt >> 4, colg = lt & 15;
    const int arow = lt >> 1, ahq = lt & 1;  // A staging: row, h-half

    float acc[8][8];
#pragma unroll
    for (int i = 0; i < 8; i++)
#pragma unroll
        for (int j = 0; j < 8; j++) acc[i][j] = 0.0f;

    const float* hA = hid + (size_t)(rowBase + arow) * HH + g * 512 + ahq * 8;

    float4 a0, a1, bv[4];
    {
        const int h0 = g * 512;
        a0 = *(const float4*)(hA);
        a1 = *(const float4*)(hA + 4);
#pragma unroll
        for (int r = 0; r < 4; ++r) {
            int idx = r * 128 + lt;
            bv[r] = *(const float4*)(Wm + (size_t)(h0 + (idx >> 5)) * KK + (idx & 31) * 4);
        }
    }

    for (int it = 0; it < 32; ++it) {
        __syncthreads();
        const int hb = ahq * 8;
        sm.s.As[g][hb + 0][arow] = a0.x;
        sm.s.As[g][hb + 1][arow] = a0.y;
        sm.s.As[g][hb + 2][arow] = a0.z;
        sm.s.As[g][hb + 3][arow] = a0.w;
        sm.s.As[g][hb + 4][arow] = a1.x;
        sm.s.As[g][hb + 5][arow] = a1.y;
        sm.s.As[g][hb + 6][arow] = a1.z;
        sm.s.As[g][hb + 7][arow] = a1.w;
#pragma unroll
        for (int r = 0; r < 4; ++r) {
            int idx = r * 128 + lt;
            *(float4*)&sm.s.Bs[g][idx >> 5][(idx & 31) * 4] = bv[r];
        }
        __syncthreads();
        if (it + 1 < 32) {
            const int h0 = g * 512 + (it + 1) * 16;
            a0 = *(const float4*)(hA + (it + 1) * 16);
            a1 = *(const float4*)(hA + (it + 1) * 16 + 4);
#pragma unroll
            for (int r = 0; r < 4; ++r) {
                int idx = r * 128 + lt;
                bv[r] = *(const float4*)(Wm + (size_t)(h0 + (idx >> 5)) * KK + (idx & 31) * 4);
            }
        }
#pragma unroll
        for (int h = 0; h < 16; ++h) {
            float4 aL = *(const float4*)&sm.s.As[g][h][rowg * 8];
            float4 aH = *(const float4*)&sm.s.As[g][h][rowg * 8 + 4];
            float4 b0 = *(const float4*)&sm.s.Bs[g][h][colg * 4];
            float4 b1 = *(const float4*)&sm.s.Bs[g][h][64 + colg * 4];
            float ar[8] = {aL.x, aL.y, aL.z, aL.w, aH.x, aH.y, aH.z, aH.w};
            float br[8] = {b0.x, b0.y, b0.z, b0.w, b1.x, b1.y, b1.z, b1.w};
#pragma unroll
            for (int i = 0; i < 8; i++)
#pragma unroll
                for (int j = 0; j < 8; j++) acc[i][j] = fmaf(ar[i], br[j], acc[i][j]);
        }
    }
    __syncthreads();
    for (int gp = 1; gp <= 3; ++gp) {
        if (g == gp) {
#pragma unroll
            for (int i = 0; i < 8; ++i) {
                sm.red[i * 2][lt] = make_float4(acc[i][0], acc[i][1], acc[i][2], acc[i][3]);
                sm.red[i * 2 + 1][lt] = make_float4(acc[i][4], acc[i][5], acc[i][6], acc[i][7]);
            }
        }
        __syncthreads();
        if (g == 0) {
#pragma unroll
            for (int i = 0; i < 8; ++i) {
                float4 r0 = sm.red[i * 2][lt];
                float4 r1 = sm.red[i * 2 + 1][lt];
                acc[i][0] += r0.x; acc[i][1] += r0.y; acc[i][2] += r0.z; acc[i][3] += r0.w;
                acc[i][4] += r1.x; acc[i][5] += r1.y; acc[i][6] += r1.z; acc[i][7] += r1.w;
            }
        }
        __syncthreads();
    }
    if (g == 0) {
        float4 bb0 = *(const float4*)(bias + colg * 4);
        float4 bb1 = *(const float4*)(bias + 64 + colg * 4);
#pragma unroll
        for (int i = 0; i < 8; ++i) {
            int row = rowBase + rowg * 8 + i;
            *(float4*)(logits + (size_t)row * KK + colg * 4) =
                make_float4(acc[i][0] + bb0.x, acc[i][1] + bb0.y, acc[i][2] + bb0.z, acc[i][3] + bb0.w);
            *(float4*)(logits + (size_t)row * KK + 64 + colg * 4) =
                make_float4(acc[i][4] + bb1.x, acc[i][5] + bb1.y, acc[i][6] + bb1.z, acc[i][7] + bb1.w);
        }
    }
}

// -------------------- Kernel B: sequential scans --------------------
// 64 blocks x 256 threads. KEY FIX (R5): every per-step __syncthreads drains
// vmcnt(0) -> any per-step global load/store eats full memory latency at the
// barrier. So: NO per-step VMEM. Emissions staged through double-buffered LDS
// in 8-step chunks (one float4/thread loaded at chunk start, written to LDS at
// chunk end); Viterbi hist stores buffered in registers (hb[8], static index
// via unrolled chunk loop) and flushed once per chunk.
struct SMemB {
    float ubuf[2][144];
    float em[2][CH * KK];   // 8 KB: staged emissions, double-buffered
    float red[4];
    float vbuf[128];
};

__global__ __launch_bounds__(256) void scan_k(const float* __restrict__ logits,
                                              const int* __restrict__ mask,
                                              const int* __restrict__ labels,
                                              const float* __restrict__ startT,
                                              const float* __restrict__ endT,
                                              const float* __restrict__ trans,
                                              float* __restrict__ shist,
                                              float* __restrict__ out) {
    __shared__ SMemB sm;
    const int tid = threadIdx.x;
    const int bid = blockIdx.x;
    const float L2E = 1.4426950408889634f;
    const int s = tid & 3;
    const int jb = tid >> 2;
    const int j0 = jb * 2;
    const int padw = j0 + 4 * (j0 >> 5);
    const int lane = tid & 63;
    const int NCHUNK = TT / CH;  // 64

    if (bid < BB) {
        // ---------- forward (log-partition), exp domain ----------
        const int b = bid;
        const float* lrow = logits + (size_t)b * TT * KK;
        unsigned long long mb[8];
#pragma unroll
        for (int c = 0; c < 8; ++c) mb[c] = __ballot(mask[b * TT + c * 64 + lane]);
        float V0[32], V1[32];
#pragma unroll
        for (int k = 0; k < 32; k++) {
            V0[k] = exp2f(trans[(s * 32 + k) * KK + j0] * L2E);
            V1[k] = exp2f(trans[(s * 32 + k) * KK + j0 + 1] * L2E);
        }
        float a0_ = (startT[j0] + lrow[j0]) * L2E;
        float a1_ = (startT[j0 + 1] + lrow[j0 + 1]) * L2E;
        float OFF = (startT[0] + lrow[0]) * L2E;  // identical on all threads
        float S0_ = exp2f(a0_ - OFF);
        float S1_ = exp2f(a1_ - OFF);
        if (s == 0) {
            sm.ubuf[0][padw] = S0_;
            sm.ubuf[0][padw + 1] = S1_;
        }
        // stage chunk 0
        float4 st = *(const float4*)(lrow + tid * 4);
        *(float4*)&sm.em[0][tid * 4] = st;
        __syncthreads();
        int cur = 0;
        for (int c = 0; c < NCHUNK; ++c) {
            const int buf = c & 1;
#pragma unroll
            for (int r = 0; r < CH; ++r) {
                const int t = c * CH + r;
                if (r == 0 && c + 1 < NCHUNK)
                    st = *(const float4*)(lrow + (size_t)(c + 1) * CH * KK + tid * 4);
                if (t > 0) {
                    int mt = (int)((mb[t >> 6] >> (t & 63)) & 1ull);
                    if (mt) {
                        float2 em = *(const float2*)&sm.em[buf][r * KK + j0];
                        const float* ub = &sm.ubuf[cur][s * 36];
                        float u00 = sm.ubuf[cur][0];
                        float uu[32];
#pragma unroll
                        for (int cc = 0; cc < 8; ++cc) {
                            float4 v = *(const float4*)(ub + cc * 4);
                            uu[cc * 4] = v.x; uu[cc * 4 + 1] = v.y; uu[cc * 4 + 2] = v.z; uu[cc * 4 + 3] = v.w;
                        }
                        float r00 = __builtin_amdgcn_rcpf(u00);
                        OFF += log2f(u00);  // off-chain, uniform across threads
                        float sc0 = exp2f(em.x * L2E) * r00;
                        float sc1 = exp2f(em.y * L2E) * r00;
                        float p0[4] = {0.f, 0.f, 0.f, 0.f}, p1[4] = {0.f, 0.f, 0.f, 0.f};
#pragma unroll
                        for (int k = 0; k < 32; k += 4) {
#pragma unroll
                            for (int q = 0; q < 4; ++q) {
                                p0[q] = fmaf(uu[k + q], V0[k + q], p0[q]);
                                p1[q] = fmaf(uu[k + q], V1[k + q], p1[q]);
                            }
                        }
                        float w0 = (p0[0] + p0[1]) + (p0[2] + p0[3]);
                        float w1 = (p1[0] + p1[1]) + (p1[2] + p1[3]);
                        w0 += __shfl_xor(w0, 1, 64);
                        w0 += __shfl_xor(w0, 2, 64);
                        w1 += __shfl_xor(w1, 1, 64);
                        w1 += __shfl_xor(w1, 2, 64);
                        S0_ = w0 * sc0;
                        S1_ = w1 * sc1;
                        if (s == 0) {
                            sm.ubuf[cur ^ 1][padw] = S0_;
                            sm.ubuf[cur ^ 1][padw + 1] = S1_;
                        }
                        cur ^= 1;
                    }
                }
                if (r == CH - 1 && c + 1 < NCHUNK)
                    *(float4*)&sm.em[buf ^ 1][tid * 4] = st;
                __syncthreads();
            }
        }
        if (s == 0) {
            sm.vbuf[j0] = log2f(S0_) + endT[j0] * L2E;
            sm.vbuf[j0 + 1] = log2f(S1_) + endT[j0 + 1] * L2E;
        }
        __syncthreads();

        // gold path score (parallel over t)
        float part = 0.0f;
        for (int tt = tid; tt < TT; tt += 256) {
            if (tt == 0) {
                int l0 = labels[b * TT];
                part += startT[l0] + lrow[l0];
            } else if (mask[b * TT + tt]) {
                int lc = labels[b * TT + tt];
                int lp = labels[b * TT + tt - 1];
                part += trans[lp * KK + lc] + lrow[(size_t)tt * KK + lc];
            }
        }
#pragma unroll
        for (int d = 1; d < 64; d <<= 1) part += __shfl_xor(part, d, 64);
        int wid = tid >> 6;
        if (lane == 0) sm.red[wid] = part;
        __syncthreads();
        if (tid < 64) {
            float v0 = sm.vbuf[tid], v1 = sm.vbuf[tid + 64];
            float mx = fmaxf(v0, v1);
#pragma unroll
            for (int d = 1; d < 64; d <<= 1) mx = fmaxf(mx, __shfl_xor(mx, d, 64));
            float p = exp2f(v0 - mx) + exp2f(v1 - mx);
#pragma unroll
            for (int d = 1; d < 64; d <<= 1) p += __shfl_xor(p, d, 64);
            if (tid == 0) {
                int total = 0;
#pragma unroll
                for (int c = 0; c < 8; ++c) total += __popcll(mb[c]);
                float score = sm.red[0] + sm.red[1] + sm.red[2] + sm.red[3];
                score += endT[labels[b * TT + total - 1]];
                float logZ = (OFF + mx + log2f(p)) * 0.6931471805599453f;
                float llh = score - logZ;
                atomicAdd(out + BB * TT, -llh * (1.0f / 32.0f));
            }
        }
    } else {
        // ---------- viterbi forward (max only; score history -> ws) ----------
        const int b = bid - BB;
        const float* lrow = logits + (size_t)b * TT * KK;
        float* hist = shist + (size_t)b * TT * KK;
        unsigned long long mb[8];
#pragma unroll
        for (int c = 0; c < 8; ++c) mb[c] = __ballot(mask[b * TT + c * 64 + lane]);
        float T0[32], T1[32];
#pragma unroll
        for (int k = 0; k < 32; k++) {
            T0[k] = trans[(s * 32 + k) * KK + j0];
            T1[k] = trans[(s * 32 + k) * KK + j0 + 1];
        }
        float s0_ = startT[j0] + lrow[j0];
        float s1_ = startT[j0 + 1] + lrow[j0 + 1];
        if (s == 0) {
            sm.ubuf[0][padw] = s0_;
            sm.ubuf[0][padw + 1] = s1_;
        }
        // stage chunk 0
        float4 st = *(const float4*)(lrow + tid * 4);
        *(float4*)&sm.em[0][tid * 4] = st;
        __syncthreads();
        int cur = 0;
        float2 hb[CH];
        for (int c = 0; c < NCHUNK; ++c) {
            const int buf = c & 1;
#pragma unroll
            for (int r = 0; r < CH; ++r) {
                const int t = c * CH + r;
                if (r == 0 && c + 1 < NCHUNK)
                    st = *(const float4*)(lrow + (size_t)(c + 1) * CH * KK + tid * 4);
                if (t > 0) {
                    int mt = (int)((mb[t >> 6] >> (t & 63)) & 1ull);
                    if (mt) {
                        float2 em = *(const float2*)&sm.em[buf][r * KK + j0];
                        const float* ub = &sm.ubuf[cur][s * 36];
                        float uu[32];
#pragma unroll
                        for (int cc = 0; cc < 8; ++cc) {
                            float4 v = *(const float4*)(ub + cc * 4);
                            uu[cc * 4] = v.x; uu[cc * 4 + 1] = v.y; uu[cc * 4 + 2] = v.z; uu[cc * 4 + 3] = v.w;
                        }
                        float m0a = -3.0e38f, m0b = -3.0e38f, m1a = -3.0e38f, m1b = -3.0e38f;
#pragma unroll
                        for (int k = 0; k < 32; k += 4) {
                            m0a = fmaxf(m0a, fmaxf(uu[k] + T0[k], uu[k + 1] + T0[k + 1]));
                            m0b = fmaxf(m0b, fmaxf(uu[k + 2] + T0[k + 2], uu[k + 3] + T0[k + 3]));
                            m1a = fmaxf(m1a, fmaxf(uu[k] + T1[k], uu[k + 1] + T1[k + 1]));
                            m1b = fmaxf(m1b, fmaxf(uu[k + 2] + T1[k + 2], uu[k + 3] + T1[k + 3]));
                        }
                        float m0 = fmaxf(m0a, m0b), m1 = fmaxf(m1a, m1b);
                        m0 = fmaxf(m0, __shfl_xor(m0, 1, 64));
                        m0 = fmaxf(m0, __shfl_xor(m0, 2, 64));
                        m1 = fmaxf(m1, __shfl_xor(m1, 1, 64));
                        m1 = fmaxf(m1, __shfl_xor(m1, 2, 64));
                        s0_ = m0 + em.x;
                        s1_ = m1 + em.y;
                        if (s == 0) {
                            sm.ubuf[cur ^ 1][padw] = s0_;
                            sm.ubuf[cur ^ 1][padw + 1] = s1_;
                        }
                        cur ^= 1;
                    }
                }
                hb[r] = make_float2(s0_, s1_);
                if (r == CH - 1 && c + 1 < NCHUNK)
                    *(float4*)&sm.em[buf ^ 1][tid * 4] = st;
                __syncthreads();
            }
            // flush this chunk's history rows (stores drain at next chunk's
            // first barrier -> amortized once per CH steps)
            if (s == 1) {
#pragma unroll
                for (int r = 0; r < CH; ++r)
                    *(float2*)(hist + (size_t)(c * CH + r) * KK + j0) = hb[r];
            }
        }
    }
}

// -------------------- Kernel C: parallel backpointer recompute --------------------
__global__ __launch_bounds__(256) void bp_k(const float* __restrict__ shist,
                                            const float* __restrict__ trans,
                                            const int* __restrict__ mask,
                                            unsigned char* __restrict__ bp) {
    const int t = blockIdx.x + 1;
    const int tid = threadIdx.x;
    const int j = tid & 127, bg = tid >> 7;
    __shared__ float sc[BB][KK];
#pragma unroll
    for (int r = 0; r < 4; ++r) {
        int f = tid + r * 256;
        int bb2 = f >> 5, c4 = (f & 31) * 4;
        *(float4*)&sc[bb2][c4] = *(const float4*)&shist[(size_t)bb2 * TT * KK + (size_t)(t - 1) * KK + c4];
    }
    __syncthreads();
    float m[16];
    int idx[16];
#pragma unroll
    for (int c = 0; c < 16; c++) { m[c] = -3.0e38f; idx[c] = 0; }
    for (int i4 = 0; i4 < 32; ++i4) {
        const int ib = i4 * 4;
        float tr0 = trans[(ib + 0) * KK + j];
        float tr1 = trans[(ib + 1) * KK + j];
        float tr2 = trans[(ib + 2) * KK + j];
        float tr3 = trans[(ib + 3) * KK + j];
#pragma unroll
        for (int c = 0; c < 16; c++) {
            float4 s4 = *(const float4*)&sc[bg + 2 * c][ib];
            float c0 = s4.x + tr0, c1 = s4.y + tr1, c2 = s4.z + tr2, c3 = s4.w + tr3;
            if (c0 > m[c]) { m[c] = c0; idx[c] = ib; }
            if (c1 > m[c]) { m[c] = c1; idx[c] = ib + 1; }
            if (c2 > m[c]) { m[c] = c2; idx[c] = ib + 2; }
            if (c3 > m[c]) { m[c] = c3; idx[c] = ib + 3; }
        }
    }
#pragma unroll
    for (int c = 0; c < 16; c++) {
        int bb2 = bg + 2 * c;
        int v = idx[c];
        if (mask[bb2 * TT + t] == 0) v = j;
        bp[(size_t)bb2 * TT * KK + (size_t)t * KK + j] = (unsigned char)v;
    }
}

// -------------------- Kernel D: backtrace via 8-wave register relay --------------------
__global__ __launch_bounds__(512) void bt_k(const float* __restrict__ shist,
                                            const float* __restrict__ endT,
                                            const unsigned char* __restrict__ bp,
                                            float* __restrict__ out) {
    const int b = blockIdx.x;
    const int tid = threadIdx.x;
    const int lane = tid & 63, w = tid >> 6;
    __shared__ float cb[128];
    __shared__ int tagbuf[512];
    __shared__ int handoff;
    if (tid < 128) cb[tid] = shist[(size_t)b * TT * KK + (size_t)(TT - 1) * KK + tid] + endT[tid];
    __syncthreads();
    if (tid == 0) {
        float mm = cb[0];
        int bi = 0;
        for (int i = 1; i < 128; i++)
            if (cb[i] > mm) { mm = cb[i]; bi = i; }
        tagbuf[TT - 1] = bi;
        handoff = bi;
    }
    unsigned int reg[64];
    const unsigned char* bpb = bp + (size_t)b * TT * KK;
#pragma unroll
    for (int r = 0; r < 64; r++) {
        int t_row = w * 64 + 1 + r;
        unsigned int v = 0;
        if (t_row < TT) v = *(const unsigned short*)(bpb + (size_t)t_row * KK + lane * 2);
        reg[r] = v;
    }
    __syncthreads();
    for (int ph = 7; ph >= 0; --ph) {
        if (w == ph) {
            int tag = handoff;
#pragma unroll
            for (int r = 63; r >= 0; --r) {
                int t_row = ph * 64 + 1 + r;
                if (t_row < TT) {
                    unsigned int vv = (unsigned int)__shfl((int)reg[r], tag >> 1, 64);
                    tag = (int)((vv >> ((tag & 1) * 8)) & 0xffu);
                    if (lane == 0) tagbuf[t_row - 1] = tag;
                }
            }
            if (lane == 0) handoff = tag;
        }
        __syncthreads();
    }
    out[b * TT + tid] = (float)tagbuf[tid];
}

// -------------------- launch --------------------
extern "C" void kernel_launch(void* const* d_in, const int* in_sizes, int n_in,
                              void* d_out, int out_size, void* d_ws, size_t ws_size,
                              hipStream_t stream) {
    const float* hid = (const float*)d_in[0];
    const int* mask = (const int*)d_in[1];
    const int* labels = (const int*)d_in[2];
    const float* Wm = (const float*)d_in[3];
    const float* bias = (const float*)d_in[4];
    const float* startT = (const float*)d_in[5];
    const float* endT = (const float*)d_in[6];
    const float* trans = (const float*)d_in[7];
    float* out = (float*)d_out;
    char* ws = (char*)d_ws;

    float* logits = (float*)ws;                              // 8,388,608 B
    float* shist = (float*)(ws + 8388608);                   // 8,388,608 B
    unsigned char* bp = (unsigned char*)(ws + 16777216);     // 2,097,152 B

    gemm_k<<<256, 512, 0, stream>>>(hid, Wm, bias, logits, out + BB * TT);
    scan_k<<<64, 256, 0, stream>>>(logits, mask, labels, startT, endT, trans, shist, out);
    bp_k<<<TT - 1, 256, 0, stream>>>(shist, trans, mask, bp);
    bt_k<<<BB, 512, 0, stream>>>(shist, endT, bp, out);
}